// Round 4
// baseline (295.812 us; speedup 1.0000x reference)
//
#include <hip/hip_runtime.h>

typedef __bf16 bf16_t;
typedef bf16_t bf16x8 __attribute__((ext_vector_type(8)));
typedef float floatx4 __attribute__((ext_vector_type(4)));

#define GN 4096
#define GK 1024
#define BM 128
#define BN 128
#define BK 32           // unpadded LDS row stride (u16) — required by global_load_lds
#define INVT (1.0f/0.03f)
#define NTILES 528      // 32*33/2 upper-tri tiles per modality
#define NCROSS 1024     // 32*32 cross tiles

// fp32 -> bf16 RNE
static __device__ __forceinline__ unsigned short f2bf(float f) {
    unsigned u = __builtin_bit_cast(unsigned, f);
    u += 0x7fffu + ((u >> 16) & 1u);
    return (unsigned short)(u >> 16);
}
static __device__ __forceinline__ float bf2f(unsigned short b) {
    return __builtin_bit_cast(float, (unsigned)b << 16);
}

// One dispatch: blocks [0,GN) = post rows (cast+inv-norm), [GN,2GN) = brand rows,
// [2GN,3GN) = cross-diag dots (recomputes bf16 quantization from fp32 inputs).
__global__ __launch_bounds__(256)
void prep_all(const float* __restrict__ brand, const float* __restrict__ post,
              unsigned short* __restrict__ brandb, unsigned short* __restrict__ postb,
              float* __restrict__ inv_brand, float* __restrict__ inv_post,
              float* __restrict__ dvec) {
    const int b = blockIdx.x, tid = threadIdx.x;
    const int wave = tid >> 6, lane = tid & 63;
    __shared__ float sw[4];
    float ss;
    if (b < 2 * GN) {
        const bool isPost = (b < GN);
        const int i = isPost ? b : b - GN;
        const float* row = (isPost ? post : brand) + (size_t)i * GK;
        unsigned short* rowb = (isPost ? postb : brandb) + (size_t)i * GK;
        float4 v = ((const float4*)row)[tid];          // 256 thr * 4 = 1024 elems
        ss = v.x * v.x + v.y * v.y + v.z * v.z + v.w * v.w;
        ushort4 o;
        o.x = f2bf(v.x); o.y = f2bf(v.y); o.z = f2bf(v.z); o.w = f2bf(v.w);
        ((ushort4*)rowb)[tid] = o;
        #pragma unroll
        for (int off = 32; off > 0; off >>= 1) ss += __shfl_down(ss, off);
        if (lane == 0) sw[wave] = ss;
        __syncthreads();
        if (tid == 0) {
            float s = sw[0] + sw[1] + sw[2] + sw[3];
            (isPost ? inv_post : inv_brand)[i] = 1.0f / sqrtf(s);
        }
    } else {
        const int i = b - 2 * GN;
        float4 p = ((const float4*)(post  + (size_t)i * GK))[tid];
        float4 q = ((const float4*)(brand + (size_t)i * GK))[tid];
        ss  = bf2f(f2bf(p.x)) * bf2f(f2bf(q.x));
        ss += bf2f(f2bf(p.y)) * bf2f(f2bf(q.y));
        ss += bf2f(f2bf(p.z)) * bf2f(f2bf(q.z));
        ss += bf2f(f2bf(p.w)) * bf2f(f2bf(q.w));
        #pragma unroll
        for (int off = 32; off > 0; off >>= 1) ss += __shfl_down(ss, off);
        if (lane == 0) sw[wave] = ss;
        __syncthreads();
        if (tid == 0) dvec[i] = sw[0] + sw[1] + sw[2] + sw[3];
    }
}

// Unified GEMM dispatch: blocks [0,NCROSS) cross tiles; then post-intra, brand-intra
// upper-tri tiles. Epilogue = shfl_xor segmented reductions + 1 atomic/lane/quantity.
__global__ __launch_bounds__(256)
void gemm_all(const unsigned short* __restrict__ postb, const unsigned short* __restrict__ brandb,
              const float* __restrict__ dvec,
              const float* __restrict__ inv_post, const float* __restrict__ inv_brand,
              float* __restrict__ sum_post, float* __restrict__ cnt_post,
              float* __restrict__ sum_brand, float* __restrict__ cnt_brand) {
    __shared__ __align__(16) unsigned short As[BM * BK];
    __shared__ __align__(16) unsigned short Bs[BN * BK];
    __shared__ float s_ia[128], s_ib[128], s_da[128], s_db[128];

    const int tid = threadIdx.x;
    const int wave = tid >> 6, lane = tid & 63;
    const int wm = (wave >> 1) * 64, wn = (wave & 1) * 64;

    int idx = blockIdx.x;
    const unsigned short *A, *B;
    float *srow, *scol, *crow, *ccol;
    int bm, bn;
    bool is_cross, do_cols;

    if (idx < NCROSS) {
        is_cross = true; do_cols = true;
        bm = (idx >> 5) * BM; bn = (idx & 31) * BN;
        A = postb; B = brandb;
        srow = sum_post; crow = cnt_post; scol = sum_brand; ccol = cnt_brand;
        if (tid < 128) { s_ia[tid] = inv_post[bm + tid] * INVT; s_da[tid] = dvec[bm + tid]; }
        else { int t2 = tid - 128; s_ib[t2] = inv_brand[bn + t2]; s_db[t2] = dvec[bn + t2]; }
    } else {
        is_cross = false;
        idx -= NCROSS;
        const unsigned short* X; const float* invx; float* sacc;
        if (idx >= NTILES) { idx -= NTILES; X = brandb; invx = inv_brand; sacc = sum_brand; }
        else               {               X = postb;  invx = inv_post;  sacc = sum_post;  }
        int J = (int)((sqrtf(8.f * idx + 1.f) - 1.f) * 0.5f);
        while ((J + 1) * (J + 2) / 2 <= idx) ++J;
        while (J * (J + 1) / 2 > idx) --J;
        const int I = idx - J * (J + 1) / 2;
        bm = I * BM; bn = J * BN;
        A = X; B = X;
        srow = sacc; scol = sacc; crow = nullptr; ccol = nullptr;
        do_cols = (I != J);
        if (tid < 128) s_ia[tid] = invx[bm + tid] * (0.8f * INVT);
        else           s_ib[tid - 128] = invx[bn + (tid - 128)];
    }
    // s_* writes are covered by the first __syncthreads in the K-loop.

    // ---- K loop: global_load_lds staging (wave-uniform base + lane*16B) ----
    const int lrow = lane & 15;
    const int kq = lane >> 4;
    const int drow = lane >> 2;        // row within 16-row DMA strip
    const int dcol = (lane & 3) * 8;   // u16 k-chunk within row
    floatx4 acc[4][4] = {};
    for (int k0 = 0; k0 < GK; k0 += BK) {
        #pragma unroll
        for (int s = 0; s < 2; ++s) {
            const int r0 = (wave * 2 + s) * 16;
            const int gr = r0 + drow;
            __builtin_amdgcn_global_load_lds(
                (const __attribute__((address_space(1))) void*)
                    (A + (size_t)(bm + gr) * GK + k0 + dcol),
                (__attribute__((address_space(3))) void*)(As + r0 * BK), 16, 0, 0);
            __builtin_amdgcn_global_load_lds(
                (const __attribute__((address_space(1))) void*)
                    (B + (size_t)(bn + gr) * GK + k0 + dcol),
                (__attribute__((address_space(3))) void*)(Bs + r0 * BK), 16, 0, 0);
        }
        __syncthreads();
        bf16x8 af[4], bfr[4];
        #pragma unroll
        for (int t = 0; t < 4; ++t)
            af[t] = *(const bf16x8*)(As + (wm + t * 16 + lrow) * BK + kq * 8);
        #pragma unroll
        for (int u = 0; u < 4; ++u)
            bfr[u] = *(const bf16x8*)(Bs + (wn + u * 16 + lrow) * BK + kq * 8);
        #pragma unroll
        for (int t = 0; t < 4; ++t)
            #pragma unroll
            for (int u = 0; u < 4; ++u)
                acc[t][u] = __builtin_amdgcn_mfma_f32_16x16x32_bf16(af[t], bfr[u],
                                                                    acc[t][u], 0, 0, 0);
        __syncthreads();
    }

    // ---- epilogue: per-lane exp/count accumulation ----
    const int cn = lane & 15, rq = lane >> 4;
    float ia_r[4][4], ib_c[4];
    #pragma unroll
    for (int t = 0; t < 4; ++t)
        #pragma unroll
        for (int r = 0; r < 4; ++r)
            ia_r[t][r] = s_ia[wm + t * 16 + rq * 4 + r];
    #pragma unroll
    for (int u = 0; u < 4; ++u)
        ib_c[u] = s_ib[wn + u * 16 + cn];

    float rsum[4][4] = {}, rcnt[4][4] = {};
    float csum[4] = {}, ccnt[4] = {};
    if (is_cross) {
        float da_r[4][4], db_c[4];
        #pragma unroll
        for (int t = 0; t < 4; ++t)
            #pragma unroll
            for (int r = 0; r < 4; ++r)
                da_r[t][r] = s_da[wm + t * 16 + rq * 4 + r];
        #pragma unroll
        for (int u = 0; u < 4; ++u)
            db_c[u] = s_db[wn + u * 16 + cn];
        #pragma unroll
        for (int t = 0; t < 4; ++t)
            #pragma unroll
            for (int u = 0; u < 4; ++u)
                #pragma unroll
                for (int r = 0; r < 4; ++r) {
                    float s = acc[t][u][r];
                    int grow = bm + wm + t * 16 + rq * 4 + r;
                    int gcol = bn + wn + u * 16 + cn;
                    float e = __expf(s * ia_r[t][r] * ib_c[u]);
                    rsum[t][r] += e;
                    csum[u] += e;
                    bool offd = (grow != gcol);
                    rcnt[t][r] += (offd && s > da_r[t][r]) ? 1.f : 0.f;
                    ccnt[u]    += (offd && s > db_c[u])    ? 1.f : 0.f;
                }
    } else {
        #pragma unroll
        for (int t = 0; t < 4; ++t)
            #pragma unroll
            for (int u = 0; u < 4; ++u)
                #pragma unroll
                for (int r = 0; r < 4; ++r) {
                    float s = acc[t][u][r];
                    int grow = bm + wm + t * 16 + rq * 4 + r;
                    int gcol = bn + wn + u * 16 + cn;
                    float e = (grow == gcol) ? 1.0f : __expf(s * ia_r[t][r] * ib_c[u]);
                    rsum[t][r] += e;
                    csum[u] += e;
                }
    }

    // ---- shfl_xor segmented reductions; each lane owns one row + one col ----
    // Rows: lanes sharing rq (16 consecutive lanes) hold partials of the same row.
    float my_rs = 0.f, my_rc = 0.f;
    #pragma unroll
    for (int t = 0; t < 4; ++t)
        #pragma unroll
        for (int r = 0; r < 4; ++r) {
            float v = rsum[t][r];
            v += __shfl_xor(v, 1); v += __shfl_xor(v, 2);
            v += __shfl_xor(v, 4); v += __shfl_xor(v, 8);
            if (cn == ((t << 2) | r)) my_rs = v;
            if (is_cross) {
                float w = rcnt[t][r];
                w += __shfl_xor(w, 1); w += __shfl_xor(w, 2);
                w += __shfl_xor(w, 4); w += __shfl_xor(w, 8);
                if (cn == ((t << 2) | r)) my_rc = w;
            }
        }
    const int myrow = bm + wm + (cn >> 2) * 16 + rq * 4 + (cn & 3);
    atomicAdd(&srow[myrow], my_rs);
    if (is_cross) atomicAdd(&crow[myrow], my_rc);

    if (do_cols) {
        // Cols: lanes sharing cn (stride-16 lanes) hold partials of the same col.
        float my_cs = 0.f, my_cc = 0.f;
        #pragma unroll
        for (int u = 0; u < 4; ++u) {
            float v = csum[u];
            v += __shfl_xor(v, 16); v += __shfl_xor(v, 32);
            if (rq == u) my_cs = v;
            if (is_cross) {
                float w = ccnt[u];
                w += __shfl_xor(w, 16); w += __shfl_xor(w, 32);
                if (rq == u) my_cc = w;
            }
        }
        const int mycol = bn + wn + rq * 16 + cn;
        atomicAdd(&scol[mycol], my_cs);
        if (is_cross) atomicAdd(&ccol[mycol], my_cc);
    }
}

// Final per-row loss assembly + global sum
__global__ __launch_bounds__(256)
void final_loss(const float* __restrict__ sum_post, const float* __restrict__ cnt_post,
                const float* __restrict__ sum_brand, const float* __restrict__ cnt_brand,
                const float* __restrict__ dvec,
                const float* __restrict__ inv_post, const float* __restrict__ inv_brand,
                float* __restrict__ out) {
    const int i = blockIdx.x * 256 + threadIdx.x;
    float dl = dvec[i] * inv_post[i] * inv_brand[i] * INVT;
    float lp = logf(sum_post[i]);
    float lb = logf(sum_brand[i]);
    float rp = 1.0f / (4096.0f - cnt_post[i]) + 1.0f;
    float rb = 1.0f / (4096.0f - cnt_brand[i]) + 1.0f;
    float loss = 0.5f * (rb * (lb - dl) + rp * (lp - dl));
    #pragma unroll
    for (int off = 32; off > 0; off >>= 1) loss += __shfl_down(loss, off);
    __shared__ float sw[4];
    int wave = threadIdx.x >> 6, lane = threadIdx.x & 63;
    if (lane == 0) sw[wave] = loss;
    __syncthreads();
    if (threadIdx.x == 0) atomicAdd(out, sw[0] + sw[1] + sw[2] + sw[3]);
}

extern "C" void kernel_launch(void* const* d_in, const int* in_sizes, int n_in,
                              void* d_out, int out_size, void* d_ws, size_t ws_size,
                              hipStream_t stream) {
    const float* brand = (const float*)d_in[0];
    const float* post  = (const float*)d_in[1];
    float* out = (float*)d_out;

    char* ws = (char*)d_ws;
    unsigned short* postb  = (unsigned short*)ws;                       // 8 MB
    unsigned short* brandb = postb + (size_t)GN * GK;                   // 8 MB
    float* inv_post  = (float*)(brandb + (size_t)GN * GK);
    float* inv_brand = inv_post + GN;
    float* dvec      = inv_brand + GN;
    float* accs      = dvec + GN;        // [sum_post, sum_brand, cnt_post, cnt_brand]
    float* sum_post  = accs;
    float* sum_brand = accs + GN;
    float* cnt_post  = accs + 2 * GN;
    float* cnt_brand = accs + 3 * GN;

    hipMemsetAsync(d_out, 0, sizeof(float) * out_size, stream);
    hipMemsetAsync(accs, 0, sizeof(float) * 4 * GN, stream);

    prep_all<<<3 * GN, 256, 0, stream>>>(brand, post, brandb, postb,
                                         inv_brand, inv_post, dvec);
    gemm_all<<<NCROSS + 2 * NTILES, 256, 0, stream>>>(postb, brandb, dvec,
                                                      inv_post, inv_brand,
                                                      sum_post, cnt_post,
                                                      sum_brand, cnt_brand);
    final_loss<<<GN / 256, 256, 0, stream>>>(sum_post, cnt_post, sum_brand, cnt_brand,
                                             dvec, inv_post, inv_brand, out);
}

// Round 5
// 219.000 us; speedup vs baseline: 1.3507x; 1.3507x over previous
//
#include <hip/hip_runtime.h>

typedef __bf16 bf16_t;
typedef bf16_t bf16x8 __attribute__((ext_vector_type(8)));
typedef float floatx4 __attribute__((ext_vector_type(4)));

#define GN 4096
#define GK 1024
#define BM 128
#define BN 128
#define BK 32           // unpadded LDS row stride (u16) — required by global_load_lds
#define INVT (1.0f/0.03f)
#define NTILES 528      // 32*33/2 upper-tri tiles per modality
#define NCROSS 1024     // 32*32 cross tiles

// fp32 -> bf16 RNE
static __device__ __forceinline__ unsigned short f2bf(float f) {
    unsigned u = __builtin_bit_cast(unsigned, f);
    u += 0x7fffu + ((u >> 16) & 1u);
    return (unsigned short)(u >> 16);
}
static __device__ __forceinline__ float bf2f(unsigned short b) {
    return __builtin_bit_cast(float, (unsigned)b << 16);
}

// One dispatch: blocks [0,GN) = post rows (cast+inv-norm), [GN,2GN) = brand rows,
// [2GN,3GN) = cross-diag dots (recomputes bf16 quantization from fp32 inputs).
__global__ __launch_bounds__(256)
void prep_all(const float* __restrict__ brand, const float* __restrict__ post,
              unsigned short* __restrict__ brandb, unsigned short* __restrict__ postb,
              float* __restrict__ inv_brand, float* __restrict__ inv_post,
              float* __restrict__ dvec) {
    const int b = blockIdx.x, tid = threadIdx.x;
    const int wave = tid >> 6, lane = tid & 63;
    __shared__ float sw[4];
    float ss;
    if (b < 2 * GN) {
        const bool isPost = (b < GN);
        const int i = isPost ? b : b - GN;
        const float* row = (isPost ? post : brand) + (size_t)i * GK;
        unsigned short* rowb = (isPost ? postb : brandb) + (size_t)i * GK;
        float4 v = ((const float4*)row)[tid];          // 256 thr * 4 = 1024 elems
        ss = v.x * v.x + v.y * v.y + v.z * v.z + v.w * v.w;
        ushort4 o;
        o.x = f2bf(v.x); o.y = f2bf(v.y); o.z = f2bf(v.z); o.w = f2bf(v.w);
        ((ushort4*)rowb)[tid] = o;
        #pragma unroll
        for (int off = 32; off > 0; off >>= 1) ss += __shfl_down(ss, off);
        if (lane == 0) sw[wave] = ss;
        __syncthreads();
        if (tid == 0) {
            float s = sw[0] + sw[1] + sw[2] + sw[3];
            (isPost ? inv_post : inv_brand)[i] = 1.0f / sqrtf(s);
        }
    } else {
        const int i = b - 2 * GN;
        float4 p = ((const float4*)(post  + (size_t)i * GK))[tid];
        float4 q = ((const float4*)(brand + (size_t)i * GK))[tid];
        ss  = bf2f(f2bf(p.x)) * bf2f(f2bf(q.x));
        ss += bf2f(f2bf(p.y)) * bf2f(f2bf(q.y));
        ss += bf2f(f2bf(p.z)) * bf2f(f2bf(q.z));
        ss += bf2f(f2bf(p.w)) * bf2f(f2bf(q.w));
        #pragma unroll
        for (int off = 32; off > 0; off >>= 1) ss += __shfl_down(ss, off);
        if (lane == 0) sw[wave] = ss;
        __syncthreads();
        if (tid == 0) dvec[i] = sw[0] + sw[1] + sw[2] + sw[3];
    }
}

// Unified GEMM dispatch: blocks [0,NCROSS) cross tiles; then post-intra, brand-intra
// upper-tri tiles. LDS tile is XOR-swizzled; epilogue is register-lean (inline
// per-row-slice shfl reduction, no [4][4] epilogue arrays).
__global__ __launch_bounds__(256)
void gemm_all(const unsigned short* __restrict__ postb, const unsigned short* __restrict__ brandb,
              const float* __restrict__ dvec,
              const float* __restrict__ inv_post, const float* __restrict__ inv_brand,
              float* __restrict__ sum_post, float* __restrict__ cnt_post,
              float* __restrict__ sum_brand, float* __restrict__ cnt_brand) {
    __shared__ __align__(16) unsigned short As[BM * BK];
    __shared__ __align__(16) unsigned short Bs[BN * BK];
    __shared__ float s_ia[128], s_ib[128], s_da[128], s_db[128];

    const int tid = threadIdx.x;
    const int wave = tid >> 6, lane = tid & 63;
    const int wm = (wave >> 1) * 64, wn = (wave & 1) * 64;

    int idx = blockIdx.x;
    const unsigned short *A, *B;
    float *srow, *scol, *crow, *ccol;
    int bm, bn;
    bool is_cross, do_cols;

    if (idx < NCROSS) {
        is_cross = true; do_cols = true;
        bm = (idx >> 5) * BM; bn = (idx & 31) * BN;
        A = postb; B = brandb;
        srow = sum_post; crow = cnt_post; scol = sum_brand; ccol = cnt_brand;
        if (tid < 128) { s_ia[tid] = inv_post[bm + tid] * INVT; s_da[tid] = dvec[bm + tid]; }
        else { int t2 = tid - 128; s_ib[t2] = inv_brand[bn + t2]; s_db[t2] = dvec[bn + t2]; }
    } else {
        is_cross = false;
        idx -= NCROSS;
        const unsigned short* X; const float* invx; float* sacc;
        if (idx >= NTILES) { idx -= NTILES; X = brandb; invx = inv_brand; sacc = sum_brand; }
        else               {               X = postb;  invx = inv_post;  sacc = sum_post;  }
        int J = (int)((sqrtf(8.f * idx + 1.f) - 1.f) * 0.5f);
        while ((J + 1) * (J + 2) / 2 <= idx) ++J;
        while (J * (J + 1) / 2 > idx) --J;
        const int I = idx - J * (J + 1) / 2;
        bm = I * BM; bn = J * BN;
        A = X; B = X;
        srow = sacc; scol = sacc; crow = nullptr; ccol = nullptr;
        do_cols = (I != J);
        if (tid < 128) s_ia[tid] = invx[bm + tid] * (0.8f * INVT);
        else           s_ib[tid - 128] = invx[bn + (tid - 128)];
    }
    // s_* writes are covered by the first __syncthreads in the K-loop.

    // ---- K loop: global_load_lds staging with XOR-swizzled LDS layout ----
    // Writer: lane l stages global chunk ((l&3)^((l>>3)&3)) of strip-row (l>>2);
    // LDS row r holds global chunk c at position c^((r>>1)&3).
    // Reader: chunk kq of row (base16+lrow) sits at position kq^((lane>>1)&3).
    const int lrow = lane & 15;
    const int kq = lane >> 4;
    const int drow = lane >> 2;                            // row within 16-row DMA strip
    const int dcol = (((lane & 3) ^ ((lane >> 3) & 3))) * 8; // swizzled source chunk (u16)
    const int swz = ((kq ^ ((lane >> 1) & 3))) * 8;        // swizzled read offset (u16)
    floatx4 acc[4][4] = {};
    for (int k0 = 0; k0 < GK; k0 += BK) {
        #pragma unroll
        for (int s = 0; s < 2; ++s) {
            const int r0 = (wave * 2 + s) * 16;
            const int gr = r0 + drow;
            __builtin_amdgcn_global_load_lds(
                (const __attribute__((address_space(1))) void*)
                    (A + (size_t)(bm + gr) * GK + k0 + dcol),
                (__attribute__((address_space(3))) void*)(As + r0 * BK), 16, 0, 0);
            __builtin_amdgcn_global_load_lds(
                (const __attribute__((address_space(1))) void*)
                    (B + (size_t)(bn + gr) * GK + k0 + dcol),
                (__attribute__((address_space(3))) void*)(Bs + r0 * BK), 16, 0, 0);
        }
        __syncthreads();
        bf16x8 af[4], bfr[4];
        #pragma unroll
        for (int t = 0; t < 4; ++t)
            af[t] = *(const bf16x8*)(As + (wm + t * 16 + lrow) * BK + swz);
        #pragma unroll
        for (int u = 0; u < 4; ++u)
            bfr[u] = *(const bf16x8*)(Bs + (wn + u * 16 + lrow) * BK + swz);
        #pragma unroll
        for (int t = 0; t < 4; ++t)
            #pragma unroll
            for (int u = 0; u < 4; ++u)
                acc[t][u] = __builtin_amdgcn_mfma_f32_16x16x32_bf16(af[t], bfr[u],
                                                                    acc[t][u], 0, 0, 0);
        __syncthreads();
    }

    // ---- register-lean epilogue ----
    // C/D layout: col = lane&15, row = (lane>>4)*4 + reg.
    const int cn = lane & 15, rq = lane >> 4;
    float ib_c[4], db_c[4];
    #pragma unroll
    for (int u = 0; u < 4; ++u) {
        int cl = wn + u * 16 + cn;
        ib_c[u] = s_ib[cl];
        db_c[u] = is_cross ? s_db[cl] : 0.f;
    }

    float csum[4] = {}, ccnt[4] = {};
    float my_rs = 0.f, my_rc = 0.f;
    #pragma unroll
    for (int t = 0; t < 4; ++t) {
        #pragma unroll
        for (int r = 0; r < 4; ++r) {
            const int rl = wm + t * 16 + rq * 4 + r;
            const float ia = s_ia[rl];
            const float da = is_cross ? s_da[rl] : 0.f;
            const int grow = bm + rl;
            float v = 0.f, w = 0.f;
            #pragma unroll
            for (int u = 0; u < 4; ++u) {
                const float s = acc[t][u][r];
                const int gcol = bn + wn + u * 16 + cn;
                const bool diag = (grow == gcol);
                float e;
                if (is_cross) {
                    e = __expf(s * ia * ib_c[u]);
                    w += (!diag && s > da) ? 1.f : 0.f;
                    ccnt[u] += (!diag && s > db_c[u]) ? 1.f : 0.f;
                } else {
                    e = diag ? 1.0f : __expf(s * ia * ib_c[u]);
                }
                v += e;
                csum[u] += e;
            }
            // reduce over the 16 lanes (same rq) holding this row's columns
            v += __shfl_xor(v, 1); v += __shfl_xor(v, 2);
            v += __shfl_xor(v, 4); v += __shfl_xor(v, 8);
            if (cn == ((t << 2) | r)) my_rs = v;
            if (is_cross) {
                w += __shfl_xor(w, 1); w += __shfl_xor(w, 2);
                w += __shfl_xor(w, 4); w += __shfl_xor(w, 8);
                if (cn == ((t << 2) | r)) my_rc = w;
            }
        }
    }
    const int myrow = bm + wm + (cn >> 2) * 16 + rq * 4 + (cn & 3);
    atomicAdd(&srow[myrow], my_rs);
    if (is_cross) atomicAdd(&crow[myrow], my_rc);

    if (do_cols) {
        // Cols: lanes sharing cn (stride-16) hold partials of the same col.
        float my_cs = 0.f, my_cc = 0.f;
        #pragma unroll
        for (int u = 0; u < 4; ++u) {
            float v = csum[u];
            v += __shfl_xor(v, 16); v += __shfl_xor(v, 32);
            if (rq == u) my_cs = v;
            if (is_cross) {
                float w = ccnt[u];
                w += __shfl_xor(w, 16); w += __shfl_xor(w, 32);
                if (rq == u) my_cc = w;
            }
        }
        const int mycol = bn + wn + rq * 16 + cn;
        atomicAdd(&scol[mycol], my_cs);
        if (is_cross) atomicAdd(&ccol[mycol], my_cc);
    }
}

// Final per-row loss assembly + global sum
__global__ __launch_bounds__(256)
void final_loss(const float* __restrict__ sum_post, const float* __restrict__ cnt_post,
                const float* __restrict__ sum_brand, const float* __restrict__ cnt_brand,
                const float* __restrict__ dvec,
                const float* __restrict__ inv_post, const float* __restrict__ inv_brand,
                float* __restrict__ out) {
    const int i = blockIdx.x * 256 + threadIdx.x;
    float dl = dvec[i] * inv_post[i] * inv_brand[i] * INVT;
    float lp = logf(sum_post[i]);
    float lb = logf(sum_brand[i]);
    float rp = 1.0f / (4096.0f - cnt_post[i]) + 1.0f;
    float rb = 1.0f / (4096.0f - cnt_brand[i]) + 1.0f;
    float loss = 0.5f * (rb * (lb - dl) + rp * (lp - dl));
    #pragma unroll
    for (int off = 32; off > 0; off >>= 1) loss += __shfl_down(loss, off);
    __shared__ float sw[4];
    int wave = threadIdx.x >> 6, lane = threadIdx.x & 63;
    if (lane == 0) sw[wave] = loss;
    __syncthreads();
    if (threadIdx.x == 0) atomicAdd(out, sw[0] + sw[1] + sw[2] + sw[3]);
}

extern "C" void kernel_launch(void* const* d_in, const int* in_sizes, int n_in,
                              void* d_out, int out_size, void* d_ws, size_t ws_size,
                              hipStream_t stream) {
    const float* brand = (const float*)d_in[0];
    const float* post  = (const float*)d_in[1];
    float* out = (float*)d_out;

    char* ws = (char*)d_ws;
    unsigned short* postb  = (unsigned short*)ws;                       // 8 MB
    unsigned short* brandb = postb + (size_t)GN * GK;                   // 8 MB
    float* inv_post  = (float*)(brandb + (size_t)GN * GK);
    float* inv_brand = inv_post + GN;
    float* dvec      = inv_brand + GN;
    float* accs      = dvec + GN;        // [sum_post, sum_brand, cnt_post, cnt_brand]
    float* sum_post  = accs;
    float* sum_brand = accs + GN;
    float* cnt_post  = accs + 2 * GN;
    float* cnt_brand = accs + 3 * GN;

    hipMemsetAsync(d_out, 0, sizeof(float) * out_size, stream);
    hipMemsetAsync(accs, 0, sizeof(float) * 4 * GN, stream);

    prep_all<<<3 * GN, 256, 0, stream>>>(brand, post, brandb, postb,
                                         inv_brand, inv_post, dvec);
    gemm_all<<<NCROSS + 2 * NTILES, 256, 0, stream>>>(postb, brandb, dvec,
                                                      inv_post, inv_brand,
                                                      sum_post, cnt_post,
                                                      sum_brand, cnt_brand);
    final_loss<<<GN / 256, 256, 0, stream>>>(sum_post, cnt_post, sum_brand, cnt_brand,
                                             dvec, inv_post, inv_brand, out);
}